// Round 3
// baseline (448.384 us; speedup 1.0000x reference)
//
#include <hip/hip_runtime.h>

#define NB 65536     // groups per batch
#define GPB 16       // groups per block: 8 lane-groups x 2 groups each (256 threads)

// Reduce-scatter a 4-vector over the 32-lane group, all by value.
// Returns full 32-lane sum of feature f4 = 2*(t&1) + ((t>>1)&1).
__device__ __forceinline__ float rs4v(float v0, float v1, float v2, float v3,
                                      bool b0, bool b1) {
    float s, r;
    s = b0 ? v0 : v2; r = __shfl_xor(s, 1); float w0 = (b0 ? v2 : v0) + r;
    s = b0 ? v1 : v3; r = __shfl_xor(s, 1); float w1 = (b0 ? v3 : v1) + r;
    s = b1 ? w0 : w1; r = __shfl_xor(s, 2); float u  = (b1 ? w1 : w0) + r;
    u += __shfl_xor(u, 4);
    u += __shfl_xor(u, 8);
    u += __shfl_xor(u, 16);
    return u;
}

// Reduce-scatter an 8-vector over 32 lanes.
// Returns full sum of feature f8 = 4*(t&1) + (t&2) + ((t>>2)&1).
__device__ __forceinline__ float rs8v(float v0, float v1, float v2, float v3,
                                      float v4, float v5, float v6, float v7,
                                      bool b0, bool b1, bool b2) {
    float s, r;
    s = b0 ? v0 : v4; r = __shfl_xor(s, 1); float w0 = (b0 ? v4 : v0) + r;
    s = b0 ? v1 : v5; r = __shfl_xor(s, 1); float w1 = (b0 ? v5 : v1) + r;
    s = b0 ? v2 : v6; r = __shfl_xor(s, 1); float w2 = (b0 ? v6 : v2) + r;
    s = b0 ? v3 : v7; r = __shfl_xor(s, 1); float w3 = (b0 ? v7 : v3) + r;
    s = b1 ? w0 : w2; r = __shfl_xor(s, 2); float x0 = (b1 ? w2 : w0) + r;
    s = b1 ? w1 : w3; r = __shfl_xor(s, 2); float x1 = (b1 ? w3 : w1) + r;
    s = b2 ? x0 : x1; r = __shfl_xor(s, 4); float u = (b2 ? x1 : x0) + r;
    u += __shfl_xor(u, 8);
    u += __shfl_xor(u, 16);
    return u;
}

// NOTE: no min-waves arg. __launch_bounds__(256, 4) made the allocator clamp
// to the 64-VGPR occupancy tier -> spills -> garbage HBM traffic (prev session
// R2/R3 counters). Leave allocation unconstrained.
__global__ __launch_bounds__(256) void agree_kernel(
    const int* __restrict__ group_inputs,
    const int* __restrict__ item_inputs,
    const int* __restrict__ group_members,
    const float* __restrict__ user_emb,
    const float* __restrict__ item_emb,
    const float* __restrict__ group_emb,
    const float* __restrict__ att_w1,
    const float* __restrict__ att_b1,
    const float* __restrict__ att_w2,
    const float* __restrict__ att_b2,
    const float* __restrict__ cls_w,
    const float* __restrict__ cls_b,
    const float* __restrict__ pred_w1,
    const float* __restrict__ pred_b1,
    const float* __restrict__ pred_w2,
    const float* __restrict__ pred_b2,
    float* __restrict__ out)
{
    // Phase-split LDS union (33280 B):
    //   phase A: att_w1 [512][16] as 32 chunks of 16 rows, chunk stride 260
    //   phase B: pred_w1 [768][8] as 48 chunks of 16 rows, chunk stride 132
    __shared__ __align__(16) float sBuf[32 * 260];

    const int tid = threadIdx.x;
    const int t = tid & 31;                     // lane within group (dims 8t..8t+7)
    const int b0 = blockIdx.x * GPB + ((tid >> 5) << 1);   // this lane-group's 2 groups

    // ---- issue all gathers early (latency hides under weight staging) ----
    const int gA  = group_inputs[b0];
    const int gB  = group_inputs[b0 + 1];
    const int itA = item_inputs[b0];
    const int itB = item_inputs[b0 + 1];
    const int4 mA = ((const int4*)group_members)[gA];
    const int4 mB = ((const int4*)group_members)[gB];

    float mbr[2][4][8];
    {
        const int mi[2][4] = {{mA.x, mA.y, mA.z, mA.w}, {mB.x, mB.y, mB.z, mB.w}};
        #pragma unroll
        for (int gg = 0; gg < 2; ++gg) {
            #pragma unroll
            for (int s = 0; s < 4; ++s) {
                const float4* p = (const float4*)user_emb + (((long)mi[gg][s]) << 6) + (t << 1);
                float4 v0 = p[0], v1 = p[1];
                mbr[gg][s][0] = v0.x; mbr[gg][s][1] = v0.y; mbr[gg][s][2] = v0.z; mbr[gg][s][3] = v0.w;
                mbr[gg][s][4] = v1.x; mbr[gg][s][5] = v1.y; mbr[gg][s][6] = v1.z; mbr[gg][s][7] = v1.w;
            }
        }
    }
    float itv[2][8];
    {
        const int ii[2] = {itA, itB};
        #pragma unroll
        for (int gg = 0; gg < 2; ++gg) {
            const float4* p = (const float4*)item_emb + (((long)ii[gg]) << 6) + (t << 1);
            float4 v0 = p[0], v1 = p[1];
            itv[gg][0] = v0.x; itv[gg][1] = v0.y; itv[gg][2] = v0.z; itv[gg][3] = v0.w;
            itv[gg][4] = v1.x; itv[gg][5] = v1.y; itv[gg][6] = v1.z; itv[gg][7] = v1.w;
        }
    }

    const bool bb0 = (t & 1), bb1 = (t & 2), bb2 = (t & 4);
    const int f4 = ((t & 1) << 1) | ((t >> 1) & 1);            // rs4v output feature
    const int f8 = ((t & 1) << 2) + (t & 2) + ((t >> 2) & 1);  // rs8v output feature
    float ab1v[4], aw2v[4];
    #pragma unroll
    for (int p = 0; p < 4; ++p) {
        ab1v[p] = att_b1[4 * p + f4];
        aw2v[p] = att_w2[4 * p + f4];
    }

    // ---- phase A: stage att_w1 ----
    {
        const float4* src = (const float4*)att_w1;       // 2048 float4
        for (int i = tid; i < 2048; i += 256) {
            float4 v = src[i];
            int r = i >> 2, cb = (i & 3) << 2;
            *(float4*)(sBuf + 260 * (r >> 4) + ((r & 15) << 4) + cb) = v;
        }
    }
    __syncthreads();

    // ---- attention MLP: 4 passes of 4 hidden units, weights shared by 2 groups ----
    const float* mbase = sBuf + 260 * (t >> 1) + ((t & 1) << 7);  // member rows 8t..8t+7
    const float* ibase = mbase + 260 * 16;                        // item rows (+256)
    float logit[2][4] = {{0.f, 0.f, 0.f, 0.f}, {0.f, 0.f, 0.f, 0.f}};
    #pragma unroll
    for (int p = 0; p < 4; ++p) {
        float acc[2][4][4], pi[2][4];
        #pragma unroll
        for (int gg = 0; gg < 2; ++gg) {
            #pragma unroll
            for (int f = 0; f < 4; ++f) {
                pi[gg][f] = 0.f;
                #pragma unroll
                for (int s = 0; s < 4; ++s) acc[gg][s][f] = 0.f;
            }
        }
        #pragma unroll
        for (int j = 0; j < 8; ++j) {
            float4 wm = *(const float4*)(mbase + (j << 4) + (p << 2));
            float4 wi = *(const float4*)(ibase + (j << 4) + (p << 2));
            #pragma unroll
            for (int gg = 0; gg < 2; ++gg) {
                #pragma unroll
                for (int s = 0; s < 4; ++s) {
                    float mv = mbr[gg][s][j];
                    acc[gg][s][0] += mv * wm.x; acc[gg][s][1] += mv * wm.y;
                    acc[gg][s][2] += mv * wm.z; acc[gg][s][3] += mv * wm.w;
                }
                float iv = itv[gg][j];
                pi[gg][0] += iv * wi.x; pi[gg][1] += iv * wi.y;
                pi[gg][2] += iv * wi.z; pi[gg][3] += iv * wi.w;
            }
        }
        #pragma unroll
        for (int gg = 0; gg < 2; ++gg) {
            float hb = rs4v(pi[gg][0], pi[gg][1], pi[gg][2], pi[gg][3], bb0, bb1)
                       + ab1v[p];
            #pragma unroll
            for (int s = 0; s < 4; ++s) {
                float h = rs4v(acc[gg][s][0], acc[gg][s][1], acc[gg][s][2], acc[gg][s][3],
                               bb0, bb1) + hb;
                logit[gg][s] += fmaxf(h, 0.f) * aw2v[p];
            }
        }
    }
    // quad all-reduce: each quad holds each pass's 4 features exactly once
    #pragma unroll
    for (int gg = 0; gg < 2; ++gg) {
        #pragma unroll
        for (int s = 0; s < 4; ++s) {
            float v = logit[gg][s];
            v += __shfl_xor(v, 1); v += __shfl_xor(v, 2);
            logit[gg][s] = v;
        }
    }

    // ---- softmax over 4 members, argmax, classifier (b2 cancels) ----
    const float cw0 = cls_w[0], cw1 = cls_w[1], cb0c = cls_b[0], cb1c = cls_b[1];
    float at[2][4]; int bestv[2], pcv[2];
    #pragma unroll
    for (int gg = 0; gg < 2; ++gg) {
        float l0 = logit[gg][0], l1 = logit[gg][1], l2 = logit[gg][2], l3 = logit[gg][3];
        float mx = fmaxf(fmaxf(l0, l1), fmaxf(l2, l3));
        float e0 = __expf(l0 - mx), e1 = __expf(l1 - mx);
        float e2 = __expf(l2 - mx), e3 = __expf(l3 - mx);
        float inv = 1.f / (e0 + e1 + e2 + e3);
        at[gg][0] = e0 * inv; at[gg][1] = e1 * inv;
        at[gg][2] = e2 * inv; at[gg][3] = e3 * inv;
        int best = 0; float bv = at[gg][0];
        if (at[gg][1] > bv) { bv = at[gg][1]; best = 1; }
        if (at[gg][2] > bv) { bv = at[gg][2]; best = 2; }
        if (at[gg][3] > bv) { bv = at[gg][3]; best = 3; }
        bestv[gg] = best;
        pcv[gg] = (bv * cw1 + cb1c) > (bv * cw0 + cb0c) ? 1 : 0;
    }

    // at_wt / pred_class written early to release registers through phase B
    if (t == 0) {
        #pragma unroll
        for (int gg = 0; gg < 2; ++gg) {
            const int b = b0 + gg;
            *(float4*)(out + NB + 4 * b) = make_float4(at[gg][0], at[gg][1], at[gg][2], at[gg][3]);
            out[5 * NB + b] = (float)pcv[gg];
        }
    }

    // group embedding gathers (latency hides under phase-B staging)
    float gvr[2][8];
    {
        const int gi2[2] = {gA, gB};
        #pragma unroll
        for (int gg = 0; gg < 2; ++gg) {
            const float4* p = (const float4*)group_emb + (((long)gi2[gg]) << 6) + (t << 1);
            float4 v0 = p[0], v1 = p[1];
            gvr[gg][0] = v0.x; gvr[gg][1] = v0.y; gvr[gg][2] = v0.z; gvr[gg][3] = v0.w;
            gvr[gg][4] = v1.x; gvr[gg][5] = v1.y; gvr[gg][6] = v1.z; gvr[gg][7] = v1.w;
        }
    }

    // ---- phase B: stage pred_w1 (overwrites sBuf) ----
    __syncthreads();
    {
        const float4* srcp = (const float4*)pred_w1;     // 1536 float4
        for (int i = tid; i < 1536; i += 256) {
            float4 v = srcp[i];
            int r = i >> 1, cb = (i & 1) << 2;
            *(float4*)(sBuf + 132 * (r >> 4) + ((r & 15) << 3) + cb) = v;
        }
    }

    // g_att while staging is in flight (mbr dies here)
    float gvec[2][8], elv[2][8];
    #pragma unroll
    for (int gg = 0; gg < 2; ++gg) {
        #pragma unroll
        for (int d = 0; d < 8; ++d) {
            float w = at[gg][0] * mbr[gg][0][d] + at[gg][1] * mbr[gg][1][d]
                    + at[gg][2] * mbr[gg][2][d] + at[gg][3] * mbr[gg][3][d];
            float ldr = mbr[gg][0][d];
            ldr = (bestv[gg] == 1) ? mbr[gg][1][d] : ldr;
            ldr = (bestv[gg] == 2) ? mbr[gg][2][d] : ldr;
            ldr = (bestv[gg] == 3) ? mbr[gg][3][d] : ldr;
            float ga = pcv[gg] ? ldr : w;
            float gv = ga + gvr[gg][d];
            gvec[gg][d] = gv;
            elv[gg][d]  = gv * itv[gg][d];
        }
    }
    __syncthreads();

    // ---- prediction MLP: [elem, g, items] (3*256) -> 8 -> 1, weights shared ----
    const float pb1v = pred_b1[f8], pw2v = pred_w2[f8], pb2v = pred_b2[0];
    const float* pbase = sBuf + 132 * (t >> 1) + ((t & 1) << 6);
    float po[2][8] = {{0.f,0.f,0.f,0.f,0.f,0.f,0.f,0.f},
                      {0.f,0.f,0.f,0.f,0.f,0.f,0.f,0.f}};
    #pragma unroll
    for (int j = 0; j < 8; ++j) {
        const float* pA = pbase + (j << 3);
        float4 a0 = *(const float4*)pA,          a1 = *(const float4*)(pA + 4);
        float4 q0 = *(const float4*)(pA + 2112), q1 = *(const float4*)(pA + 2116);
        float4 c0 = *(const float4*)(pA + 4224), c1 = *(const float4*)(pA + 4228);
        #pragma unroll
        for (int gg = 0; gg < 2; ++gg) {
            float e = elv[gg][j], gv = gvec[gg][j], iv = itv[gg][j];
            po[gg][0] += e * a0.x; po[gg][0] += gv * q0.x; po[gg][0] += iv * c0.x;
            po[gg][1] += e * a0.y; po[gg][1] += gv * q0.y; po[gg][1] += iv * c0.y;
            po[gg][2] += e * a0.z; po[gg][2] += gv * q0.z; po[gg][2] += iv * c0.z;
            po[gg][3] += e * a0.w; po[gg][3] += gv * q0.w; po[gg][3] += iv * c0.w;
            po[gg][4] += e * a1.x; po[gg][4] += gv * q1.x; po[gg][4] += iv * c1.x;
            po[gg][5] += e * a1.y; po[gg][5] += gv * q1.y; po[gg][5] += iv * c1.y;
            po[gg][6] += e * a1.z; po[gg][6] += gv * q1.z; po[gg][6] += iv * c1.z;
            po[gg][7] += e * a1.w; po[gg][7] += gv * q1.w; po[gg][7] += iv * c1.w;
        }
    }

    float yv[2];
    #pragma unroll
    for (int gg = 0; gg < 2; ++gg) {
        float poR = rs8v(po[gg][0], po[gg][1], po[gg][2], po[gg][3],
                         po[gg][4], po[gg][5], po[gg][6], po[gg][7],
                         bb0, bb1, bb2);
        float z = fmaxf(poR + pb1v, 0.f) * pw2v;
        z += __shfl_xor(z, 1); z += __shfl_xor(z, 2); z += __shfl_xor(z, 4);
        z += pb2v;
        yv[gg] = 1.f / (1.f + __expf(-z));
    }

    if (t == 0) {
        out[b0]     = yv[0];
        out[b0 + 1] = yv[1];
    }
}

extern "C" void kernel_launch(void* const* d_in, const int* in_sizes, int n_in,
                              void* d_out, int out_size, void* d_ws, size_t ws_size,
                              hipStream_t stream) {
    (void)in_sizes; (void)n_in; (void)out_size; (void)d_ws; (void)ws_size;
    agree_kernel<<<NB / GPB, 256, 0, stream>>>(
        (const int*)d_in[0], (const int*)d_in[1], (const int*)d_in[2],
        (const float*)d_in[3], (const float*)d_in[4], (const float*)d_in[5],
        (const float*)d_in[6], (const float*)d_in[7], (const float*)d_in[8],
        (const float*)d_in[9], (const float*)d_in[10], (const float*)d_in[11],
        (const float*)d_in[12], (const float*)d_in[13], (const float*)d_in[14],
        (const float*)d_in[15], (float*)d_out);
}